// Round 4
// baseline (385.201 us; speedup 1.0000x reference)
//
#include <hip/hip_runtime.h>
#include <stdint.h>
#include <stddef.h>

typedef __bf16 bf16;
typedef __bf16 bf16x4 __attribute__((ext_vector_type(4)));
typedef __bf16 bf16x8 __attribute__((ext_vector_type(8)));
typedef float f32x4 __attribute__((ext_vector_type(4)));

#define MFMA(a, b, c) __builtin_amdgcn_mfma_f32_16x16x32_bf16(a, b, c, 0, 0, 0)

static constexpr int kB = 4, kN = 4096, kC = 1024, kH = 16, kD = 64;
static constexpr int kM = kB * kN;   // 16384 token rows
static constexpr int kK = 1024;      // contraction dim for both GEMMs
static constexpr int kQKVN = 3072;

// async 16B global->LDS (direct-to-LDS DMA; dest = wave-uniform base + lane*16)
__device__ __forceinline__ void cp16(const void* g, void* l) {
  __builtin_amdgcn_global_load_lds(
      (const __attribute__((address_space(1))) void*)g,
      (__attribute__((address_space(3))) void*)l, 16, 0, 0);
}

// fp32 -> bf16 elementwise convert, 4 elems/thread
__global__ __launch_bounds__(256) void cvt_bf16(const float* __restrict__ src,
                                                bf16* __restrict__ dst, int n4) {
  const int i = blockIdx.x * 256 + threadIdx.x;
  if (i < n4) {
    const float4 v = ((const float4*)src)[i];
    bf16x4 o = {(bf16)v.x, (bf16)v.y, (bf16)v.z, (bf16)v.w};
    *(bf16x4*)&dst[4 * i] = o;
  }
}

// rope on 8 consecutive d-elements (4 aligned pairs)
__device__ __forceinline__ bf16x8 rope8(bf16x8 t, bf16x8 f) {
  bf16x8 o;
#pragma unroll
  for (int p = 0; p < 4; ++p) {
    float t0 = (float)t[2 * p], t1 = (float)t[2 * p + 1];
    float f0 = (float)f[2 * p], f1 = (float)f[2 * p + 1];
    o[2 * p]     = (bf16)(t0 * f0 - t1 * f1);
    o[2 * p + 1] = (bf16)(t1 * f0 + t0 * f1);
  }
  return o;
}

// C[m][n] = sum_k A[m][k] * Bw[n][k] (+ bias[n]).  A: kM x kK, Bw: NOUT x kK (bf16 row-major).
//
// ONE-BARRIER-PER-K-TILE counted-vmcnt schedule (T1+T3+T4+T5), coalesced swizzled staging:
//   256x256 tile, BK=32, 8 waves (2M x 4N, each 128x64 out), ring of 4 LDS K-tile
//   buffers (32 KB each = 128 KB, 1 block/CU).
//   Per K-tile t: { stage(t+3) [4 cp16] ; ds_read 12 b128 of tile t ; s_waitcnt vmcnt(8)
//                   ; setprio(1) 32 MFMA setprio(0) ; s_barrier }
//   Why no barrier before the MFMAs: tile t was staged at t-3; EVERY wave's own cp16s
//   for tile t+1 are confirmed by its vmcnt(8) at tile t, which precedes the end-of-tile
//   barrier -> that single barrier publishes all waves' confirmations. WAR: stage(t+3)
//   rewrites the buffer last READ at tile t-1; each wave's t-1 reads complete before its
//   t-1 MFMAs (lgkm), which precede the end-of-(t-1) barrier; stage(t+3) is after it.
//   Max inter-wave drift < 1 tile. Tail waits: vmcnt(8)...(8),4,0 (in-flight 12->8->4->0).
//   Fewer sync points => a wave's MFMA burst can cover its SIMD-partner's read window.
//   LDS layout per tile: [row 0..255][4 slots x 16B] (one row = one 64B line);
//   slot s holds k-chunk kb = s ^ ((row>>1)&3): coalesced cp16 (4 lanes = 1 full line),
//   conflict-free swizzled b128 fragment reads (XOR term lane-constant across frags).
template <int NOUT, bool BIAS, typename OutT>
__global__ __launch_bounds__(512, 2) void gemm_bt(const bf16* __restrict__ A,
                                                  const bf16* __restrict__ Bw,
                                                  const float* __restrict__ bias,
                                                  OutT* __restrict__ Cout) {
  __shared__ unsigned short As[4][256 * 32];  // 16 KB per buf: [row][slot*8 + e]
  __shared__ unsigned short Bs[4][256 * 32];
  const int tid = threadIdx.x;
  const int wave = tid >> 6, lane = tid & 63;
  const int q4 = lane >> 4, l16 = lane & 15;
  const int wr = wave >> 2, wc = wave & 3;

  const int nwg = gridDim.x * gridDim.y;
  int bid = blockIdx.y * gridDim.x + blockIdx.x;
  bid = (bid & 7) * (nwg >> 3) + (bid >> 3);
  const int bx = bid % gridDim.x, by = bid / gridDim.x;
  const int n0 = bx * 256, m0 = by * 256;

  constexpr int NT = kK / 32;  // 32 K-tiles

  f32x4 acc[8][4] = {};

  auto stageA = [&](int kt) {
    const int buf = kt & 3;
#pragma unroll
    for (int i = 0; i < 2; ++i) {
      const int c = i * 512 + tid;            // 0..1023, linear LDS dest (c*16 B)
      const int row = c >> 2, s = c & 3;      // 4 lanes per row = one 64B line
      const int kb = s ^ ((row >> 1) & 3);    // inverse-swizzled source chunk
      cp16(A + (size_t)(m0 + row) * kK + kt * 32 + kb * 8, &As[buf][c * 8]);
    }
  };
  auto stageB = [&](int kt) {
    const int buf = kt & 3;
#pragma unroll
    for (int i = 0; i < 2; ++i) {
      const int c = i * 512 + tid;
      const int row = c >> 2, s = c & 3;
      const int kb = s ^ ((row >> 1) & 3);
      cp16(Bw + (size_t)(n0 + row) * kK + kt * 32 + kb * 8, &Bs[buf][c * 8]);
    }
  };

  // prologue: tiles 0..2 staged (12 cp16/thread in flight); confirm tile 0; publish
  stageA(0); stageB(0); stageA(1); stageB(1); stageA(2); stageB(2);
  asm volatile("s_waitcnt vmcnt(8)\n\ts_barrier" ::: "memory");

  const int slot8 = (q4 ^ ((l16 >> 1) & 3)) * 8;
  const int arow = wr * 128 + l16;  // + i*16
  const int bcol = wc * 64 + l16;   // + j*16

  for (int t = 0; t < NT; ++t) {
    const int rb = t & 3;
    // stage first: start the long-latency vmem ops earliest
    if (t + 3 < NT) { stageA(t + 3); stageB(t + 3); }
    // all 12 fragment reads of tile t (compiler fine-schedules lgkm waits into MFMAs)
    bf16x8 a[8], b[4];
#pragma unroll
    for (int i = 0; i < 8; ++i)
      a[i] = *(const bf16x8*)&As[rb][(arow + i * 16) * 32 + slot8];
#pragma unroll
    for (int j = 0; j < 4; ++j)
      b[j] = *(const bf16x8*)&Bs[rb][(bcol + j * 16) * 32 + slot8];
    // confirm NEXT tile's staging (own cp16s); end-of-tile barrier publishes to all
    if (t < NT - 3)
      asm volatile("s_waitcnt vmcnt(8)" ::: "memory");
    else if (t == NT - 3)
      asm volatile("s_waitcnt vmcnt(4)" ::: "memory");
    else
      asm volatile("s_waitcnt vmcnt(0)" ::: "memory");
    __builtin_amdgcn_s_setprio(1);
#pragma unroll
    for (int i = 0; i < 8; ++i)
#pragma unroll
      for (int j = 0; j < 4; ++j) acc[i][j] = MFMA(a[i], b[j], acc[i][j]);
    __builtin_amdgcn_s_setprio(0);
    asm volatile("s_barrier" ::: "memory");
  }

  // epilogue: C/D layout col=lane&15, row=(lane>>4)*4+reg
#pragma unroll
  for (int i = 0; i < 8; ++i) {
    const int rowb = m0 + wr * 128 + i * 16 + q4 * 4;
#pragma unroll
    for (int j = 0; j < 4; ++j) {
      const int col = n0 + wc * 64 + j * 16 + l16;
      const float bv = BIAS ? bias[col] : 0.0f;
#pragma unroll
      for (int r = 0; r < 4; ++r)
        Cout[(size_t)(rowb + r) * NOUT + col] = (OutT)(acc[i][j][r] + bv);
    }
  }
}

// One block per (b,h,w) window. 4 waves x 64 q-rows, q-groups of 16 rows.
// SWAPPED-OPERAND flash attention: S^T = mfma(K, Q) so each lane owns the
// token axis (softmax axis) for one query column q=l16:
//  - softmax: 31 in-lane ops + 2 shfl_xor (vs 32 bpermutes)
//  - P round-trip: lane's 4 values = 4 consecutive tokens -> packed b64 writes
//    into pT[q][tok] (XOR-swizzled, conflict-free), b128 reads as PV A-frag
//  - V transpose staging XOR-swizzled: 16-way write conflict -> conflict-free
__global__ __launch_bounds__(256) void attn_win(const bf16* __restrict__ qkv,
                                                const bf16* __restrict__ freqs,
                                                bf16* __restrict__ ob) {
  __shared__ unsigned short k8[8 * 128 * 8];  // [dblk][tok][8]  16 KB (roped K)
  __shared__ unsigned short v8[16 * 64 * 8];  // [tokblk][d^swz][8] 16 KB (V^T)
  __shared__ unsigned short pT[4][16 * 128];  // per wave [q:16][tok:128] 4 KB

  const int bid = blockIdx.x;
  const int w = bid & 15, h = (bid >> 4) & 15, b = bid >> 8;
  const int n0 = w * 256;
  const int tid = threadIdx.x;
  const int wave = tid >> 6, lane = tid & 63;
  const int q4 = lane >> 4, l16 = lane & 15;
  const float scale = 0.125f;  // D^-0.5
  const int swz = (l16 & 7) << 4;  // byte XOR for pT (bits 4-6)
  char* const pw = (char*)&pT[wave][0];

  // q fragments with rope, hoisted (B-frag: col=l16=q, k=(q4)*8+e, s picks d-half)
  bf16x8 qf[4][2];
#pragma unroll
  for (int g = 0; g < 4; ++g) {
    const int n = n0 + wave * 64 + g * 16 + l16;
    const bf16* qrow = qkv + (size_t)(b * kN + n) * kQKVN + h * kD;
    const bf16* frow = freqs + (size_t)n * kD;
#pragma unroll
    for (int s = 0; s < 2; ++s) {
      const int d0 = s * 32 + q4 * 8;
      qf[g][s] = rope8(*(const bf16x8*)(qrow + d0), *(const bf16x8*)(frow + d0));
    }
  }

  f32x4 O[4][4] = {};       // [group][d-tile]; rows q=q4*4+r, cols d=l16+16*jd
  float mrow[4], lrow[4];   // per-lane stats for q = g*16 + l16
#pragma unroll
  for (int g = 0; g < 4; ++g) { mrow[g] = -3.0e38f; lrow[g] = 0.0f; }

  for (int c = 0; c < 2; ++c) {
    const int nc = n0 + c * 128;
    __syncthreads();  // previous chunk's reads done before restaging
#pragma unroll
    for (int i = 0; i < 4; ++i) {
      const int cid = i * 256 + tid;
      const int tok = cid & 127, db = cid >> 7;
      const int n = nc + tok;
      const size_t base = (size_t)(b * kN + n) * kQKVN + h * kD + db * 8;
      bf16x8 kv = *(const bf16x8*)(qkv + base + kC);  // K slice
      bf16x8 fv = *(const bf16x8*)(freqs + (size_t)n * kD + db * 8);
      *(bf16x8*)&k8[(db * 128 + tok) * 8] = rope8(kv, fv);
      bf16x8 vv = *(const bf16x8*)(qkv + base + 2 * kC);  // V slice
      const int tb = tok >> 3, sl = tok & 7;
#pragma unroll
      for (int e = 0; e < 8; ++e) {
        const int d = db * 8 + e;
        ((bf16*)v8)[((tb * 64) + (d ^ (tb & 7))) * 8 + sl] = vv[e];
      }
    }
    __syncthreads();

#pragma unroll
    for (int g = 0; g < 4; ++g) {
      // S^T = K Q^T over d=64: lane holds toks {j*16 + q4*4 + r} for q = g*16+l16
      f32x4 S[8] = {};
#pragma unroll
      for (int j = 0; j < 8; ++j)
#pragma unroll
        for (int s = 0; s < 2; ++s) {
          bf16x8 kf = *(const bf16x8*)&k8[((q4 + 4 * s) * 128 + j * 16 + l16) * 8];
          S[j] = MFMA(kf, qf[g][s], S[j]);  // swapped operands
        }
      // scale + in-lane max over 32 tokens (4 parallel chains), then cross-q4
      float m0_ = -3.0e38f, m1_ = -3.0e38f, m2_ = -3.0e38f, m3_ = -3.0e38f;
#pragma unroll
      for (int j = 0; j < 8; ++j) {
        S[j][0] *= scale; S[j][1] *= scale; S[j][2] *= scale; S[j][3] *= scale;
        m0_ = fmaxf(m0_, S[j][0]); m1_ = fmaxf(m1_, S[j][1]);
        m2_ = fmaxf(m2_, S[j][2]); m3_ = fmaxf(m3_, S[j][3]);
      }
      float mx = fmaxf(fmaxf(m0_, m1_), fmaxf(m2_, m3_));
      mx = fmaxf(mx, __shfl_xor(mx, 16));
      mx = fmaxf(mx, __shfl_xor(mx, 32));
      const float mnew = fmaxf(mrow[g], mx);
      const float al = __expf(mrow[g] - mnew);
      mrow[g] = mnew;
      float s0 = 0.f, s1 = 0.f, s2 = 0.f, s3 = 0.f;
#pragma unroll
      for (int j = 0; j < 8; ++j) {
        S[j][0] = __expf(S[j][0] - mnew); s0 += S[j][0];
        S[j][1] = __expf(S[j][1] - mnew); s1 += S[j][1];
        S[j][2] = __expf(S[j][2] - mnew); s2 += S[j][2];
        S[j][3] = __expf(S[j][3] - mnew); s3 += S[j][3];
      }
      float sm = (s0 + s1) + (s2 + s3);
      sm += __shfl_xor(sm, 16);
      sm += __shfl_xor(sm, 32);
      lrow[g] = lrow[g] * al + sm;
      // redistribute alpha to O-row owners (O rows are q = q4*4+r; al lives at lane l16=q)
      float alr[4];
#pragma unroll
      for (int r = 0; r < 4; ++r) alr[r] = __shfl(al, q4 * 4 + r);
#pragma unroll
      for (int jd = 0; jd < 4; ++jd)
#pragma unroll
        for (int r = 0; r < 4; ++r) O[g][jd][r] *= alr[r];
      // P writes: 8 x b64, layout pT[q=l16][tok], swizzled; lane's 4 r = 4 consecutive toks
#pragma unroll
      for (int j = 0; j < 8; ++j) {
        bf16x4 pk = {(bf16)S[j][0], (bf16)S[j][1], (bf16)S[j][2], (bf16)S[j][3]};
        *(bf16x4*)(pw + l16 * 256 + ((j * 32 + q4 * 8) ^ swz)) = pk;
      }
      asm volatile("s_waitcnt lgkmcnt(0)" ::: "memory");  // P writes visible (same wave)
      // O += P V: pf = A-frag [row=q=l16][k=tok=s4*32+q4*8+e] via swizzled b128
#pragma unroll
      for (int s4 = 0; s4 < 4; ++s4) {
        bf16x8 pf = *(const bf16x8*)(pw + l16 * 256 + ((s4 * 64 + q4 * 16) ^ swz));
        const int tb2 = q4 + 4 * s4;
#pragma unroll
        for (int jd = 0; jd < 4; ++jd) {
          const int d2 = (l16 + 16 * jd) ^ (tb2 & 7);
          bf16x8 vf = *(const bf16x8*)&v8[(tb2 * 64 + d2) * 8];
          O[g][jd] = MFMA(pf, vf, O[g][jd]);
        }
      }
      asm volatile("" ::: "memory");  // keep next g's pT writes after this g's reads
    }
  }

  // epilogue: normalize (lrow lives at lane l16=q; O rows are q=q4*4+r), write bf16
#pragma unroll
  for (int g = 0; g < 4; ++g) {
    float lr[4];
#pragma unroll
    for (int r = 0; r < 4; ++r) lr[r] = __shfl(lrow[g], q4 * 4 + r);
    const int nb = n0 + wave * 64 + g * 16 + q4 * 4;
#pragma unroll
    for (int jd = 0; jd < 4; ++jd) {
      const int d = l16 + 16 * jd;
#pragma unroll
      for (int r = 0; r < 4; ++r) {
        const float v = O[g][jd][r] / lr[r];
        ob[(size_t)(b * kN + nb + r) * kC + h * kD + d] = (bf16)v;
      }
    }
  }
}

extern "C" void kernel_launch(void* const* d_in, const int* in_sizes, int n_in,
                              void* d_out, int out_size, void* d_ws, size_t ws_size,
                              hipStream_t stream) {
  (void)in_sizes; (void)n_in; (void)out_size; (void)ws_size;
  const float* x      = (const float*)d_in[0];
  const float* freqs  = (const float*)d_in[1];
  const float* qkv_w  = (const float*)d_in[2];
  const float* proj_w = (const float*)d_in[3];
  const float* proj_b = (const float*)d_in[4];
  float* out = (float*)d_out;

  // workspace layout (bf16 elems):
  //  [qkv_buf: kM*kQKVN][shared: kM*kC (x_bf16 then attn_buf)][qkvw][projw][freqs]
  bf16* qkv_buf = (bf16*)d_ws;
  bf16* shared  = qkv_buf + (size_t)kM * kQKVN;
  bf16* x_b     = shared;                     // live: convert -> gemm1
  bf16* attn_b  = shared;                     // live: attn -> gemm2
  bf16* qkvw_b  = shared + (size_t)kM * kC;
  bf16* projw_b = qkvw_b + (size_t)kQKVN * kC;
  bf16* freqs_b = projw_b + (size_t)kC * kC;

  // fp32 -> bf16 conversions
  cvt_bf16<<<(kM * kC / 4 + 255) / 256, 256, 0, stream>>>(x, x_b, kM * kC / 4);
  cvt_bf16<<<(kQKVN * kC / 4 + 255) / 256, 256, 0, stream>>>(qkv_w, qkvw_b, kQKVN * kC / 4);
  cvt_bf16<<<(kC * kC / 4 + 255) / 256, 256, 0, stream>>>(proj_w, projw_b, kC * kC / 4);
  cvt_bf16<<<(kN * kD / 4 + 255) / 256, 256, 0, stream>>>(freqs, freqs_b, kN * kD / 4);

  gemm_bt<kQKVN, false, bf16><<<dim3(kQKVN / 256, kM / 256), 512, 0, stream>>>(
      x_b, qkvw_b, nullptr, qkv_buf);
  attn_win<<<dim3(kB * kH * (kN / 256)), 256, 0, stream>>>(qkv_buf, freqs_b, attn_b);
  gemm_bt<kC, true, float><<<dim3(kC / 256, kM / 256), 512, 0, stream>>>(
      attn_b, projw_b, proj_b, out);
}

// Round 5
// 364.245 us; speedup vs baseline: 1.0575x; 1.0575x over previous
//
#include <hip/hip_runtime.h>
#include <stdint.h>
#include <stddef.h>

typedef __bf16 bf16;
typedef __bf16 bf16x4 __attribute__((ext_vector_type(4)));
typedef __bf16 bf16x8 __attribute__((ext_vector_type(8)));
typedef float f32x4 __attribute__((ext_vector_type(4)));

#define MFMA(a, b, c) __builtin_amdgcn_mfma_f32_16x16x32_bf16(a, b, c, 0, 0, 0)

static constexpr int kB = 4, kN = 4096, kC = 1024, kH = 16, kD = 64;
static constexpr int kM = kB * kN;   // 16384 token rows
static constexpr int kK = 1024;      // contraction dim for both GEMMs
static constexpr int kQKVN = 3072;

// async 16B global->LDS (direct-to-LDS DMA; dest = wave-uniform base + lane*16)
__device__ __forceinline__ void cp16(const void* g, void* l) {
  __builtin_amdgcn_global_load_lds(
      (const __attribute__((address_space(1))) void*)g,
      (__attribute__((address_space(3))) void*)l, 16, 0, 0);
}

// fp32 -> bf16 elementwise convert, 4 elems/thread
__global__ __launch_bounds__(256) void cvt_bf16(const float* __restrict__ src,
                                                bf16* __restrict__ dst, int n4) {
  const int i = blockIdx.x * 256 + threadIdx.x;
  if (i < n4) {
    const float4 v = ((const float4*)src)[i];
    bf16x4 o = {(bf16)v.x, (bf16)v.y, (bf16)v.z, (bf16)v.w};
    *(bf16x4*)&dst[4 * i] = o;
  }
}

// rope on 8 consecutive d-elements (4 aligned pairs)
__device__ __forceinline__ bf16x8 rope8(bf16x8 t, bf16x8 f) {
  bf16x8 o;
#pragma unroll
  for (int p = 0; p < 4; ++p) {
    float t0 = (float)t[2 * p], t1 = (float)t[2 * p + 1];
    float f0 = (float)f[2 * p], f1 = (float)f[2 * p + 1];
    o[2 * p]     = (bf16)(t0 * f0 - t1 * f1);
    o[2 * p + 1] = (bf16)(t1 * f0 + t0 * f1);
  }
  return o;
}

// C[m][n] = sum_k A[m][k] * Bw[n][k] (+ bias[n]).  A: kM x kK, Bw: NOUT x kK (bf16 row-major).
//
// TWO-PHASE counted-vmcnt schedule (round-2 structure, proven 124us) with ONE
// vmcnt wait per K-tile (m201 discipline: counted waits at tile granularity only):
//   256x256 tile, BK=32, 8 waves (2M x 4N, each 128x64 out), ring of 4 LDS K-tile
//   buffers (32 KB each = 128 KB, 1 block/CU).
//   tile t, phase 0: { ds_read A frags + B cols 0..31 ; stageA(t+3) ; s_barrier ;
//                      setprio(1) 16 MFMA setprio(0) ; s_barrier }
//   tile t, phase 1: { ds_read B cols 32..63 ; stageB(t+3) ; s_waitcnt vmcnt(8) ;
//                      s_barrier ; setprio(1) 16 MFMA setprio(0) ; s_barrier }
//   The single vmcnt(8) at ph1 confirms tile t+1's A AND B (12 outstanding -> 8);
//   the following barrier publishes all waves' confirmations; first read of t+1 is
//   at tile t+1 ph0, after it. WAR: stage(t+3) rewrites buf[(t-1)&3], whose last
//   reads precede the end-of-(t-1) barriers. Tail: t==NT-3 -> vmcnt(4),
//   t>=NT-2 -> vmcnt(0) (stages stop after NT-1 is issued at t==NT-4).
//   LDS layout per tile: [row 0..255][4 slots x 16B] (one row = one 64B line);
//   slot s holds k-chunk kb = s ^ ((row>>1)&3): coalesced cp16 (4 lanes = 1 full
//   line) and conflict-free swizzled b128 fragment reads (XOR term lane-constant).
template <int NOUT, bool BIAS, typename OutT>
__global__ __launch_bounds__(512, 2) void gemm_bt(const bf16* __restrict__ A,
                                                  const bf16* __restrict__ Bw,
                                                  const float* __restrict__ bias,
                                                  OutT* __restrict__ Cout) {
  __shared__ unsigned short As[4][256 * 32];  // 16 KB per buf: [row][slot*8 + e]
  __shared__ unsigned short Bs[4][256 * 32];
  const int tid = threadIdx.x;
  const int wave = tid >> 6, lane = tid & 63;
  const int q4 = lane >> 4, l16 = lane & 15;
  const int wr = wave >> 2, wc = wave & 3;

  const int nwg = gridDim.x * gridDim.y;
  int bid = blockIdx.y * gridDim.x + blockIdx.x;
  bid = (bid & 7) * (nwg >> 3) + (bid >> 3);
  const int bx = bid % gridDim.x, by = bid / gridDim.x;
  const int n0 = bx * 256, m0 = by * 256;

  constexpr int NT = kK / 32;  // 32 K-tiles

  f32x4 acc[8][4] = {};

  auto stageA = [&](int kt) {
    const int buf = kt & 3;
#pragma unroll
    for (int i = 0; i < 2; ++i) {
      const int c = i * 512 + tid;            // 0..1023, linear LDS dest (c*16 B)
      const int row = c >> 2, s = c & 3;      // 4 lanes per row = one 64B line
      const int kb = s ^ ((row >> 1) & 3);    // inverse-swizzled source chunk
      cp16(A + (size_t)(m0 + row) * kK + kt * 32 + kb * 8, &As[buf][c * 8]);
    }
  };
  auto stageB = [&](int kt) {
    const int buf = kt & 3;
#pragma unroll
    for (int i = 0; i < 2; ++i) {
      const int c = i * 512 + tid;
      const int row = c >> 2, s = c & 3;
      const int kb = s ^ ((row >> 1) & 3);
      cp16(Bw + (size_t)(n0 + row) * kK + kt * 32 + kb * 8, &Bs[buf][c * 8]);
    }
  };

  stageA(0); stageB(0); stageA(1); stageB(1); stageA(2); stageB(2);
  asm volatile("s_waitcnt vmcnt(8)\n\ts_barrier" ::: "memory");

  const int slot8 = (q4 ^ ((l16 >> 1) & 3)) * 8;
  const int arow = wr * 128 + l16;  // + i*16
  const int bcol = wc * 64 + l16;   // + j*16

  for (int t = 0; t < NT; ++t) {
    const int rb = t & 3;
    // ---- phase 0: A frags + B cols 0..31; stage A-half of K-tile t+3; NO vmcnt
    bf16x8 a[8], b0, b1;
#pragma unroll
    for (int i = 0; i < 8; ++i)
      a[i] = *(const bf16x8*)&As[rb][(arow + i * 16) * 32 + slot8];
    b0 = *(const bf16x8*)&Bs[rb][bcol * 32 + slot8];
    b1 = *(const bf16x8*)&Bs[rb][(bcol + 16) * 32 + slot8];
    if (t + 3 < NT) stageA(t + 3);
    asm volatile("s_barrier" ::: "memory");
    __builtin_amdgcn_s_setprio(1);
#pragma unroll
    for (int i = 0; i < 8; ++i) {
      acc[i][0] = MFMA(a[i], b0, acc[i][0]);
      acc[i][1] = MFMA(a[i], b1, acc[i][1]);
    }
    __builtin_amdgcn_s_setprio(0);
    asm volatile("s_barrier" ::: "memory");

    // ---- phase 1: B cols 32..63; stage B-half of K-tile t+3; ONE vmcnt per tile
    bf16x8 b2 = *(const bf16x8*)&Bs[rb][(bcol + 32) * 32 + slot8];
    bf16x8 b3 = *(const bf16x8*)&Bs[rb][(bcol + 48) * 32 + slot8];
    if (t + 3 < NT) stageB(t + 3);
    if (t < NT - 3)
      asm volatile("s_waitcnt vmcnt(8)\n\ts_barrier" ::: "memory");
    else if (t == NT - 3)
      asm volatile("s_waitcnt vmcnt(4)\n\ts_barrier" ::: "memory");
    else
      asm volatile("s_waitcnt vmcnt(0)\n\ts_barrier" ::: "memory");
    __builtin_amdgcn_s_setprio(1);
#pragma unroll
    for (int i = 0; i < 8; ++i) {
      acc[i][2] = MFMA(a[i], b2, acc[i][2]);
      acc[i][3] = MFMA(a[i], b3, acc[i][3]);
    }
    __builtin_amdgcn_s_setprio(0);
    asm volatile("s_barrier" ::: "memory");
  }

  // epilogue: C/D layout col=lane&15, row=(lane>>4)*4+reg
#pragma unroll
  for (int i = 0; i < 8; ++i) {
    const int rowb = m0 + wr * 128 + i * 16 + q4 * 4;
#pragma unroll
    for (int j = 0; j < 4; ++j) {
      const int col = n0 + wc * 64 + j * 16 + l16;
      const float bv = BIAS ? bias[col] : 0.0f;
#pragma unroll
      for (int r = 0; r < 4; ++r)
        Cout[(size_t)(rowb + r) * NOUT + col] = (OutT)(acc[i][j][r] + bv);
    }
  }
}

// One block per (b,h,w) window. 4 waves x 64 q-rows, q-groups of 16 rows.
// SWAPPED-OPERAND flash attention: S^T = mfma(K, Q) so each lane owns the
// token axis (softmax axis) for one query column q=l16:
//  - softmax: 31 in-lane ops + 2 shfl_xor (vs 32 bpermutes)
//  - P round-trip: lane's 4 values = 4 consecutive tokens -> packed b64 writes
//    into pT[q][tok] (XOR-swizzled, conflict-free), b128 reads as PV A-frag
//  - V transpose staging XOR-swizzled: 16-way write conflict -> conflict-free
__global__ __launch_bounds__(256) void attn_win(const bf16* __restrict__ qkv,
                                                const bf16* __restrict__ freqs,
                                                bf16* __restrict__ ob) {
  __shared__ unsigned short k8[8 * 128 * 8];  // [dblk][tok][8]  16 KB (roped K)
  __shared__ unsigned short v8[16 * 64 * 8];  // [tokblk][d^swz][8] 16 KB (V^T)
  __shared__ unsigned short pT[4][16 * 128];  // per wave [q:16][tok:128] 4 KB

  const int bid = blockIdx.x;
  const int w = bid & 15, h = (bid >> 4) & 15, b = bid >> 8;
  const int n0 = w * 256;
  const int tid = threadIdx.x;
  const int wave = tid >> 6, lane = tid & 63;
  const int q4 = lane >> 4, l16 = lane & 15;
  const float scale = 0.125f;  // D^-0.5
  const int swz = (l16 & 7) << 4;  // byte XOR for pT (bits 4-6)
  char* const pw = (char*)&pT[wave][0];

  // q fragments with rope, hoisted (B-frag: col=l16=q, k=(q4)*8+e, s picks d-half)
  bf16x8 qf[4][2];
#pragma unroll
  for (int g = 0; g < 4; ++g) {
    const int n = n0 + wave * 64 + g * 16 + l16;
    const bf16* qrow = qkv + (size_t)(b * kN + n) * kQKVN + h * kD;
    const bf16* frow = freqs + (size_t)n * kD;
#pragma unroll
    for (int s = 0; s < 2; ++s) {
      const int d0 = s * 32 + q4 * 8;
      qf[g][s] = rope8(*(const bf16x8*)(qrow + d0), *(const bf16x8*)(frow + d0));
    }
  }

  f32x4 O[4][4] = {};       // [group][d-tile]; rows q=q4*4+r, cols d=l16+16*jd
  float mrow[4], lrow[4];   // per-lane stats for q = g*16 + l16
#pragma unroll
  for (int g = 0; g < 4; ++g) { mrow[g] = -3.0e38f; lrow[g] = 0.0f; }

  for (int c = 0; c < 2; ++c) {
    const int nc = n0 + c * 128;
    __syncthreads();  // previous chunk's reads done before restaging
#pragma unroll
    for (int i = 0; i < 4; ++i) {
      const int cid = i * 256 + tid;
      const int tok = cid & 127, db = cid >> 7;
      const int n = nc + tok;
      const size_t base = (size_t)(b * kN + n) * kQKVN + h * kD + db * 8;
      bf16x8 kv = *(const bf16x8*)(qkv + base + kC);  // K slice
      bf16x8 fv = *(const bf16x8*)(freqs + (size_t)n * kD + db * 8);
      *(bf16x8*)&k8[(db * 128 + tok) * 8] = rope8(kv, fv);
      bf16x8 vv = *(const bf16x8*)(qkv + base + 2 * kC);  // V slice
      const int tb = tok >> 3, sl = tok & 7;
#pragma unroll
      for (int e = 0; e < 8; ++e) {
        const int d = db * 8 + e;
        ((bf16*)v8)[((tb * 64) + (d ^ (tb & 7))) * 8 + sl] = vv[e];
      }
    }
    __syncthreads();

#pragma unroll
    for (int g = 0; g < 4; ++g) {
      // S^T = K Q^T over d=64: lane holds toks {j*16 + q4*4 + r} for q = g*16+l16
      f32x4 S[8] = {};
#pragma unroll
      for (int j = 0; j < 8; ++j)
#pragma unroll
        for (int s = 0; s < 2; ++s) {
          bf16x8 kf = *(const bf16x8*)&k8[((q4 + 4 * s) * 128 + j * 16 + l16) * 8];
          S[j] = MFMA(kf, qf[g][s], S[j]);  // swapped operands
        }
      // scale + in-lane max over 32 tokens (4 parallel chains), then cross-q4
      float m0_ = -3.0e38f, m1_ = -3.0e38f, m2_ = -3.0e38f, m3_ = -3.0e38f;
#pragma unroll
      for (int j = 0; j < 8; ++j) {
        S[j][0] *= scale; S[j][1] *= scale; S[j][2] *= scale; S[j][3] *= scale;
        m0_ = fmaxf(m0_, S[j][0]); m1_ = fmaxf(m1_, S[j][1]);
        m2_ = fmaxf(m2_, S[j][2]); m3_ = fmaxf(m3_, S[j][3]);
      }
      float mx = fmaxf(fmaxf(m0_, m1_), fmaxf(m2_, m3_));
      mx = fmaxf(mx, __shfl_xor(mx, 16));
      mx = fmaxf(mx, __shfl_xor(mx, 32));
      const float mnew = fmaxf(mrow[g], mx);
      const float al = __expf(mrow[g] - mnew);
      mrow[g] = mnew;
      float s0 = 0.f, s1 = 0.f, s2 = 0.f, s3 = 0.f;
#pragma unroll
      for (int j = 0; j < 8; ++j) {
        S[j][0] = __expf(S[j][0] - mnew); s0 += S[j][0];
        S[j][1] = __expf(S[j][1] - mnew); s1 += S[j][1];
        S[j][2] = __expf(S[j][2] - mnew); s2 += S[j][2];
        S[j][3] = __expf(S[j][3] - mnew); s3 += S[j][3];
      }
      float sm = (s0 + s1) + (s2 + s3);
      sm += __shfl_xor(sm, 16);
      sm += __shfl_xor(sm, 32);
      lrow[g] = lrow[g] * al + sm;
      // redistribute alpha to O-row owners (O rows are q = q4*4+r; al lives at lane l16=q)
      float alr[4];
#pragma unroll
      for (int r = 0; r < 4; ++r) alr[r] = __shfl(al, q4 * 4 + r);
#pragma unroll
      for (int jd = 0; jd < 4; ++jd)
#pragma unroll
        for (int r = 0; r < 4; ++r) O[g][jd][r] *= alr[r];
      // P writes: 8 x b64, layout pT[q=l16][tok], swizzled; lane's 4 r = 4 consecutive toks
#pragma unroll
      for (int j = 0; j < 8; ++j) {
        bf16x4 pk = {(bf16)S[j][0], (bf16)S[j][1], (bf16)S[j][2], (bf16)S[j][3]};
        *(bf16x4*)(pw + l16 * 256 + ((j * 32 + q4 * 8) ^ swz)) = pk;
      }
      asm volatile("s_waitcnt lgkmcnt(0)" ::: "memory");  // P writes visible (same wave)
      // O += P V: pf = A-frag [row=q=l16][k=tok=s4*32+q4*8+e] via swizzled b128
#pragma unroll
      for (int s4 = 0; s4 < 4; ++s4) {
        bf16x8 pf = *(const bf16x8*)(pw + l16 * 256 + ((s4 * 64 + q4 * 16) ^ swz));
        const int tb2 = q4 + 4 * s4;
#pragma unroll
        for (int jd = 0; jd < 4; ++jd) {
          const int d2 = (l16 + 16 * jd) ^ (tb2 & 7);
          bf16x8 vf = *(const bf16x8*)&v8[(tb2 * 64 + d2) * 8];
          O[g][jd] = MFMA(pf, vf, O[g][jd]);
        }
      }
      asm volatile("" ::: "memory");  // keep next g's pT writes after this g's reads
    }
  }

  // epilogue: normalize (lrow lives at lane l16=q; O rows are q=q4*4+r), write bf16
#pragma unroll
  for (int g = 0; g < 4; ++g) {
    float lr[4];
#pragma unroll
    for (int r = 0; r < 4; ++r) lr[r] = __shfl(lrow[g], q4 * 4 + r);
    const int nb = n0 + wave * 64 + g * 16 + q4 * 4;
#pragma unroll
    for (int jd = 0; jd < 4; ++jd) {
      const int d = l16 + 16 * jd;
#pragma unroll
      for (int r = 0; r < 4; ++r) {
        const float v = O[g][jd][r] / lr[r];
        ob[(size_t)(b * kN + nb + r) * kC + h * kD + d] = (bf16)v;
      }
    }
  }
}

extern "C" void kernel_launch(void* const* d_in, const int* in_sizes, int n_in,
                              void* d_out, int out_size, void* d_ws, size_t ws_size,
                              hipStream_t stream) {
  (void)in_sizes; (void)n_in; (void)out_size; (void)ws_size;
  const float* x      = (const float*)d_in[0];
  const float* freqs  = (const float*)d_in[1];
  const float* qkv_w  = (const float*)d_in[2];
  const float* proj_w = (const float*)d_in[3];
  const float* proj_b = (const float*)d_in[4];
  float* out = (float*)d_out;

  // workspace layout (bf16 elems):
  //  [qkv_buf: kM*kQKVN][shared: kM*kC (x_bf16 then attn_buf)][qkvw][projw][freqs]
  bf16* qkv_buf = (bf16*)d_ws;
  bf16* shared  = qkv_buf + (size_t)kM * kQKVN;
  bf16* x_b     = shared;                     // live: convert -> gemm1
  bf16* attn_b  = shared;                     // live: attn -> gemm2
  bf16* qkvw_b  = shared + (size_t)kM * kC;
  bf16* projw_b = qkvw_b + (size_t)kQKVN * kC;
  bf16* freqs_b = projw_b + (size_t)kC * kC;

  // fp32 -> bf16 conversions
  cvt_bf16<<<(kM * kC / 4 + 255) / 256, 256, 0, stream>>>(x, x_b, kM * kC / 4);
  cvt_bf16<<<(kQKVN * kC / 4 + 255) / 256, 256, 0, stream>>>(qkv_w, qkvw_b, kQKVN * kC / 4);
  cvt_bf16<<<(kC * kC / 4 + 255) / 256, 256, 0, stream>>>(proj_w, projw_b, kC * kC / 4);
  cvt_bf16<<<(kN * kD / 4 + 255) / 256, 256, 0, stream>>>(freqs, freqs_b, kN * kD / 4);

  gemm_bt<kQKVN, false, bf16><<<dim3(kQKVN / 256, kM / 256), 512, 0, stream>>>(
      x_b, qkvw_b, nullptr, qkv_buf);
  attn_win<<<dim3(kB * kH * (kN / 256)), 256, 0, stream>>>(qkv_buf, freqs_b, attn_b);
  gemm_bt<kC, true, float><<<dim3(kC / 256, kM / 256), 512, 0, stream>>>(
      attn_b, projw_b, proj_b, out);
}